// Round 6
// baseline (590.490 us; speedup 1.0000x reference)
//
#include <hip/hip_runtime.h>
#include <hip/hip_bf16.h>
#include <stdint.h>

#define N_IN   256
#define HEADS  8
#define OUTF   32
#define HF     256   // HEADS*OUTF
#define NEG    0.2f

// ---- counting-sort CSR build params ----
#define SHIFT  7          // 128 dst nodes per coarse bucket
#define BMASK  127
#define NBKT   128        // dsts per bucket
#define NBMAX  1024       // max coarse buckets supported (N <= 131072)
#define TILE   8192       // edges per bin_scatter block
#define CAP    4864       // per-bucket slab capacity (mean ~4092, sigma ~64)

typedef __attribute__((ext_vector_type(8))) short  s16x8;
typedef __attribute__((ext_vector_type(4))) float  f32x4;
typedef __attribute__((ext_vector_type(4))) unsigned int u32x4;

__device__ __forceinline__ unsigned short f2b(float f) {
    unsigned int u = __float_as_uint(f);
    unsigned int r = (u + 0x7fffu + ((u >> 16) & 1u)) >> 16;
    return (unsigned short)r;
}
__device__ __forceinline__ float b2f(unsigned short u) {
    union { unsigned int i; float f; } x; x.i = ((unsigned int)u) << 16; return x.f;
}

// ---- diagnostic: fill output with sentinel ----
__global__ __launch_bounds__(256) void probe_fill(float* __restrict__ out, int n, float val)
{
    int i = blockIdx.x * blockDim.x + threadIdx.x;
    if (i < n) out[i] = val;
}

// ---- W fp32 -> bf16, once (65536 elements) ----
__global__ __launch_bounds__(256) void cvt_w(const float* __restrict__ W,
                                             unsigned short* __restrict__ Wb, int n)
{
    int i = blockIdx.x * blockDim.x + threadIdx.x;
    if (i < n) Wb[i] = f2b(W[i]);
}

// ---------------- GEMM: h = feat @ W^T, fused el/er + int8 quantization ---------
// (unchanged from round 5)
__global__ __launch_bounds__(256) void gemm_h(
    const float* __restrict__ feat,
    const unsigned short* __restrict__ Wb,
    const float* __restrict__ attn_l,
    const float* __restrict__ attn_r,
    unsigned char* __restrict__ h8,
    float* __restrict__ hscale,
    float* __restrict__ el, float* __restrict__ er,
    int* __restrict__ flag, int N)
{
    __shared__ unsigned short hs[4][16][260];   // 33.3 KB/block, per-wave slice
    int wave = (blockIdx.x * blockDim.x + threadIdx.x) >> 6;
    int lane = threadIdx.x & 63;
    int w    = (threadIdx.x >> 6) & 3;
    int m0 = wave * 16;
    if (m0 >= N) return;
    int mr = lane & 15;   // m (A) / n (B) within 16
    int kg = lane >> 4;   // k-group 0..3

    const float* ap = feat + (size_t)(m0 + mr) * N_IN + kg * 8;
    bool bad = false;
    s16x8 a[8];
#pragma unroll
    for (int kk = 0; kk < 8; kk++) {
        f32x4 lo = __builtin_nontemporal_load((const f32x4*)(ap + kk * 32));
        f32x4 hi = __builtin_nontemporal_load((const f32x4*)(ap + kk * 32 + 4));
#pragma unroll
        for (int j = 0; j < 4; j++) {
            bad |= ((__float_as_uint(lo[j]) >> 23) & 0xFF) >= 0x90;
            bad |= ((__float_as_uint(hi[j]) >> 23) & 0xFF) >= 0x90;
        }
        s16x8 r;
        r[0] = (short)f2b(lo[0]); r[1] = (short)f2b(lo[1]);
        r[2] = (short)f2b(lo[2]); r[3] = (short)f2b(lo[3]);
        r[4] = (short)f2b(hi[0]); r[5] = (short)f2b(hi[1]);
        r[6] = (short)f2b(hi[2]); r[7] = (short)f2b(hi[3]);
        a[kk] = r;
    }
    if (__ballot(bad) != 0ull && lane == 0) atomicOr(flag, 1);

    f32x4 acc[16];
#pragma unroll
    for (int nt = 0; nt < 16; nt++) {
        acc[nt] = (f32x4){0.f, 0.f, 0.f, 0.f};
        const unsigned short* bp = Wb + (size_t)(nt * 16 + mr) * N_IN + kg * 8;
#pragma unroll
        for (int kk = 0; kk < 8; kk++) {
            s16x8 b = *(const s16x8*)(bp + kk * 32);
            acc[nt] = __builtin_amdgcn_mfma_f32_16x16x32_bf16(a[kk], b, acc[nt], 0, 0, 0);
        }
    }
    // C/D layout (m89-verified): col = lane&15 (=n), row = (lane>>4)*4 + r (=m)
#pragma unroll
    for (int nt = 0; nt < 16; nt++) {
        int col = nt * 16 + mr;
#pragma unroll
        for (int r = 0; r < 4; r++) {
            int row = kg * 4 + r;
            hs[w][row][col] = f2b(acc[nt][r]);
        }
    }
    // el/er from the wave's own LDS tile (no barrier: same-wave producer).
    {
        int row = lane >> 2, hd4 = lane & 3;
#pragma unroll
        for (int p = 0; p < 2; p++) {
            int hd = hd4 + p * 4;
            const unsigned short* hp = &hs[w][row][hd * OUTF];
            const float* al = attn_l + hd * OUTF;
            const float* ar = attn_r + hd * OUTF;
            float sl = 0.f, sr = 0.f;
#pragma unroll
            for (int i = 0; i < 4; i++) {
                s16x8 hv = *(const s16x8*)(hp + i * 8);
                f32x4 al0 = *(const f32x4*)(al + i * 8);
                f32x4 al1 = *(const f32x4*)(al + i * 8 + 4);
                f32x4 ar0 = *(const f32x4*)(ar + i * 8);
                f32x4 ar1 = *(const f32x4*)(ar + i * 8 + 4);
#pragma unroll
                for (int j = 0; j < 4; j++) {
                    float v = b2f((unsigned short)hv[j]);
                    sl += v * al0[j]; sr += v * ar0[j];
                }
#pragma unroll
                for (int j = 0; j < 4; j++) {
                    float v = b2f((unsigned short)hv[4 + j]);
                    sl += v * al1[j]; sr += v * ar1[j];
                }
            }
            el[(size_t)(m0 + row) * HEADS + hd] = sl;
            er[(size_t)(m0 + row) * HEADS + hd] = sr;
        }
    }
    // int8 quantize: lane -> (row = lane>>2, quarter q4 = lane&3, 64 feats each)
    {
        int row = lane >> 2, q4 = lane & 3;
        unsigned int mxb = 0;
#pragma unroll
        for (int i = 0; i < 8; i++) {
            s16x8 hv = *(const s16x8*)(&hs[w][row][q4 * 64 + i * 8]);
#pragma unroll
            for (int j = 0; j < 8; j++) {
                unsigned int b = ((unsigned int)(unsigned short)hv[j]) & 0x7fffu;
                mxb = b > mxb ? b : mxb;
            }
        }
        mxb = max(mxb, (unsigned int)__shfl_xor((int)mxb, 1));
        mxb = max(mxb, (unsigned int)__shfl_xor((int)mxb, 2));
        float mx = b2f((unsigned short)mxb);
        float scale = mx * (1.0f / 127.0f);
        float invs  = (mx > 0.f) ? 127.0f / mx : 0.f;
        if (q4 == 0) hscale[m0 + row] = scale;
#pragma unroll
        for (int c = 0; c < 4; c++) {      // 4 chunks of 16 feats -> 16 B store
            u32x4 wout;
#pragma unroll
            for (int p = 0; p < 4; p++) {
                unsigned int wrd = 0;
#pragma unroll
                for (int k = 0; k < 4; k++) {
                    float v = b2f(hs[w][row][q4 * 64 + c * 16 + p * 4 + k]);
                    int qi = (int)rintf(v * invs) + 128;
                    qi = min(max(qi, 0), 255);
                    wrd |= ((unsigned int)qi) << (8 * k);
                }
                wout[p] = wrd;
            }
            *(u32x4*)(h8 + (size_t)(m0 + row) * HF + q4 * 64 + c * 16) = wout;
        }
    }
}

// ================ CSR build phase 1: scatter edges into per-bucket slabs ==========
// Per-block LDS counting sort by coarse bucket; one global atomic per
// (block,bucket) reserves slab space mid[b*CAP + pos].
// mid entry packs (src << 7) | (dst & 127); requires N < 2^24.
__global__ __launch_bounds__(256) void bin_scatter(
    const int* __restrict__ src, const int* __restrict__ dst,
    int* __restrict__ bucket_cursor, unsigned int* __restrict__ mid,
    int* __restrict__ flag, int E, int N, int NB)
{
    __shared__ int hist[NBMAX];    // counts, then exclusive local base
    __shared__ int cur[NBMAX];
    __shared__ int gbase[NBMAX];
    __shared__ int part[256];
    __shared__ unsigned int  sorted[TILE];
    __shared__ unsigned short sortedb[TILE];
    int t = threadIdx.x;
#pragma unroll
    for (int i = t; i < NBMAX; i += 256) hist[i] = 0;
    __syncthreads();
    int tb = blockIdx.x * TILE;
    int cnt = min(TILE, E - tb);

    // pass 1: count buckets in tile
#pragma unroll
    for (int i = 0; i < TILE / 256; i++) {
        int e = tb + t + i * 256;
        if (e < E) {
            int d = __builtin_nontemporal_load(&dst[e]);
            d = min(max(d, 0), N - 1);
            atomicAdd(&hist[d >> SHIFT], 1);
        }
    }
    __syncthreads();

    // reserve slab space per bucket (cursor zero-init; final value = count)
    for (int b = t; b < NB; b += 256) {
        int c = hist[b];
        int gb = c ? atomicAdd(&bucket_cursor[b], c) : 0;
        gbase[b] = gb;
        if (c && gb + c > CAP) atomicOr(flag, 1);   // slab overflow -> poison
    }

    // exclusive scan of hist (NBMAX=1024 entries, 4 per thread);
    // safe: hist is overwritten only after the scan's first barrier, which all
    // threads reach only after their reserve-reads above.
    int b0 = 4 * t;
    int c0 = hist[b0], c1 = hist[b0 + 1], c2 = hist[b0 + 2], c3 = hist[b0 + 3];
    int s01 = c0 + c1, sall = s01 + c2 + c3;
    part[t] = sall;
    __syncthreads();
    for (int off = 1; off < 256; off <<= 1) {
        int y = (t >= off) ? part[t - off] : 0;
        __syncthreads();
        part[t] += y;
        __syncthreads();
    }
    int pb = part[t] - sall;               // exclusive over 4-groups
    hist[b0]     = pb;           cur[b0]     = pb;
    hist[b0 + 1] = pb + c0;      cur[b0 + 1] = pb + c0;
    hist[b0 + 2] = pb + s01;     cur[b0 + 2] = pb + s01;
    hist[b0 + 3] = pb + s01 + c2; cur[b0 + 3] = pb + s01 + c2;
    __syncthreads();

    // pass 2: place tile's edges into LDS grouped by bucket
#pragma unroll
    for (int i = 0; i < TILE / 256; i++) {
        int e = tb + t + i * 256;
        if (e < E) {
            int d = dst[e]; d = min(max(d, 0), N - 1);
            int s = src[e]; s = min(max(s, 0), N - 1);
            int b = d >> SHIFT;
            int p = atomicAdd(&cur[b], 1);
            sorted[p]  = ((unsigned int)s << SHIFT) | (unsigned int)(d & BMASK);
            sortedb[p] = (unsigned short)b;
        }
    }
    __syncthreads();

    // write out: consecutive i within a bucket -> consecutive slab addresses
    for (int i = t; i < cnt; i += 256) {
        int b = sortedb[i];
        int idx = gbase[b] + (i - hist[b]);
        if (idx < CAP) mid[(size_t)b * CAP + idx] = sorted[i];
    }
}

// ======== Fused bucket-sort + aggregate: one block per coarse bucket ========
// Stage slab -> LDS, build 128-entry local CSR (hist+scan), place src ids into
// sorted LDS array, then 8 waves gather h8 rows (wave-per-dst, 4 edges/group,
// 1-deep data pipeline; edge indices come from LDS = cheap lgkm loads).
// num_i = sum_j (a_j*scale_j)*u_ji - 128*sum_j(a_j*scale_j); out = num/sum(a)+bias.
__global__ __launch_bounds__(512) void aggregate(
    const unsigned char* __restrict__ h8,
    const float* __restrict__ hscale,
    const float* __restrict__ el, const float* __restrict__ er,
    const int* __restrict__ bucket_cursor,
    const unsigned int* __restrict__ mid,
    const float* __restrict__ bias,
    const int* __restrict__ flag,
    float* __restrict__ out, int N)
{
    __shared__ unsigned int raw[CAP];   // 19 KB
    __shared__ unsigned int srt[CAP];   // 19 KB
    __shared__ int hist[NBKT];
    __shared__ int scn[NBKT];
    __shared__ int cur[NBKT];
    int b = blockIdx.x, t = threadIdx.x;
    if (t < NBKT) hist[t] = 0;
    __syncthreads();
    int cnt = min(bucket_cursor[b], CAP);
    const unsigned int* ms = mid + (size_t)b * CAP;
    for (int i = t; i < cnt; i += 512) {
        unsigned int v = __builtin_nontemporal_load(&ms[i]);
        raw[i] = v;
        atomicAdd(&hist[v & BMASK], 1);
    }
    __syncthreads();
    // inclusive scan of hist -> scn (threads 0..127 active, barriers uniform)
    if (t < NBKT) scn[t] = hist[t];
    __syncthreads();
    for (int off = 1; off < NBKT; off <<= 1) {
        int y = (t < NBKT && t >= off) ? scn[t - off] : 0;
        __syncthreads();
        if (t < NBKT) scn[t] += y;
        __syncthreads();
    }
    if (t < NBKT) cur[t] = scn[t] - hist[t];   // exclusive base
    __syncthreads();
    // place src ids grouped by local dst
    for (int i = t; i < cnt; i += 512) {
        unsigned int v = raw[i];
        int p = atomicAdd(&cur[v & BMASK], 1);
        srt[p] = v >> SHIFT;
    }
    __syncthreads();

    // ---- gather phase: wave-per-dst ----
    int wave = t >> 6, lane = t & 63;
    int slot = lane >> 4;
    int g    = lane & 15;
    int hg   = g >> 1;
    int flagv = flag[0];

    for (int ld = wave; ld < NBKT; ld += 8) {
        int node = (b << SHIFT) + ld;
        if (node >= N) break;               // only trailing dsts of last bucket
        int e1 = scn[ld];
        int e0 = e1 - hist[ld];
        float er_d = er[node * HEADS + hg];
        float s_acc = 0.f, sb_acc = 0.f;
        float acc[16];
#pragma unroll
        for (int i = 0; i < 16; i++) acc[i] = 0.f;

        if (e0 < e1) {
            int jA = e0 + slot;
            bool vA = jA < e1;
            int snA = (int)srt[min(jA, e1 - 1)];
            snA = vA ? snA : 0;
            float elA = el[snA * HEADS + hg];
            float scA = hscale[snA];
            u32x4 hA = *(const u32x4*)(h8 + (size_t)snA * HF + g * 16);

            for (int j0 = e0; j0 < e1; j0 += 4) {
                int jB = j0 + 4 + slot;
                bool vB = jB < e1;
                int snB = (int)srt[min(jB, e1 - 1)];
                snB = vB ? snB : 0;
                float elB = el[snB * HEADS + hg];
                float scB = hscale[snB];
                u32x4 hB = *(const u32x4*)(h8 + (size_t)snB * HF + g * 16);
                __builtin_amdgcn_sched_barrier(0);   // pin load-issue before compute
                float e = elA + er_d;
                e = fmaxf(e, NEG * e);               // leaky relu, NEG in (0,1)
                float a = vA ? __expf(e) : 0.f;
                s_acc += a;
                float as2 = a * scA;
                sb_acc += as2;
#pragma unroll
                for (int p = 0; p < 4; p++) {        // decode 16 biased-uint8
                    unsigned int wrd = hA[p];
                    acc[p*4+0] += as2 * (float)(wrd & 0xffu);
                    acc[p*4+1] += as2 * (float)((wrd >> 8) & 0xffu);
                    acc[p*4+2] += as2 * (float)((wrd >> 16) & 0xffu);
                    acc[p*4+3] += as2 * (float)(wrd >> 24);
                }
                vA = vB; elA = elB; scA = scB; hA = hB;
            }
        }

        s_acc += __shfl_xor(s_acc, 16);
        s_acc += __shfl_xor(s_acc, 32);
        sb_acc += __shfl_xor(sb_acc, 16);
        sb_acc += __shfl_xor(sb_acc, 32);
#pragma unroll
        for (int i = 0; i < 16; i++) {
            acc[i] += __shfl_xor(acc[i], 16);
            acc[i] += __shfl_xor(acc[i], 32);
        }
        float inv = (s_acc > 0.f) ? 1.f / s_acc : 0.f;

        if (slot == 0) {
            int fo = g * 16;
            bool badv = !__builtin_isfinite(s_acc);
            float vbuf[16];
#pragma unroll
            for (int i = 0; i < 16; i++) {
                float v = (acc[i] - 128.0f * sb_acc) * inv + bias[fo + i];
                badv |= !__builtin_isfinite(v);
                vbuf[i] = v;
            }
            if (flagv) {
#pragma unroll
                for (int i = 0; i < 16; i++) vbuf[i] = 555.0f;
            } else if (badv) {
#pragma unroll
                for (int i = 0; i < 16; i++) vbuf[i] = 777.0f;
            }
#pragma unroll
            for (int q = 0; q < 4; q++) {
                f32x4 o = { vbuf[q*4+0], vbuf[q*4+1], vbuf[q*4+2], vbuf[q*4+3] };
                __builtin_nontemporal_store(o, (f32x4*)(out + (size_t)node * HF + fo + q * 4));
            }
        }
    }
}

extern "C" void kernel_launch(void* const* d_in, const int* in_sizes, int n_in,
                              void* d_out, int out_size, void* d_ws, size_t ws_size,
                              hipStream_t stream)
{
    const float* feat   = (const float*)d_in[0];
    const int*   src    = (const int*)d_in[1];
    const int*   dst    = (const int*)d_in[2];
    const float* fc_w   = (const float*)d_in[3];
    const float* attn_l = (const float*)d_in[4];
    const float* attn_r = (const float*)d_in[5];
    const float* bias   = (const float*)d_in[6];
    float* out = (float*)d_out;

    const int N = in_sizes[0] / N_IN;
    const int E = in_sizes[1];
    const int NB = (N + NBKT - 1) >> SHIFT;

    char* ws = (char*)d_ws;
    size_t off = 0;
    auto alloc = [&](size_t bytes) -> char* {
        char* p = ws + off;
        off = (off + bytes + 255) & ~(size_t)255;
        return p;
    };
    // bucket_cursor + flag contiguous -> single memset
    int* bucket_cursor = (int*)alloc((size_t)NBMAX * 4 + 256);
    int* flag          = bucket_cursor + NBMAX;
    unsigned int* mid  = (unsigned int*)alloc((size_t)NB * CAP * 4);
    float* el          = (float*)alloc((size_t)N * HEADS * 4);
    float* er          = (float*)alloc((size_t)N * HEADS * 4);
    unsigned char* h8  = (unsigned char*)alloc((size_t)N * HF);
    float* hscale      = (float*)alloc((size_t)N * 4);
    unsigned short* Wb = (unsigned short*)alloc((size_t)HF * N_IN * 2);

    if (off > ws_size || NB > NBMAX || N >= (1 << 24)) {
        probe_fill<<<(out_size + 255) / 256, 256, 0, stream>>>(out, out_size, 999.0f);
        return;
    }

    hipMemsetAsync(bucket_cursor, 0, (size_t)NBMAX * 4 + 256, stream);

    cvt_w<<<(HF * N_IN + 255) / 256, 256, 0, stream>>>(fc_w, Wb, HF * N_IN);
    {   // GEMM + fused el/er + int8 quantize: one wave per 16 rows
        int waves = (N + 15) / 16;
        int blocks = (waves + 3) / 4;
        gemm_h<<<blocks, 256, 0, stream>>>(feat, Wb, attn_l, attn_r, h8, hscale, el, er, flag, N);
    }
    // CSR phase 1: slab scatter
    int tiles = (E + TILE - 1) / TILE;
    bin_scatter<<<tiles, 256, 0, stream>>>(src, dst, bucket_cursor, mid, flag, E, N, NB);
    // fused bucket-sort + aggregate: one block per bucket
    aggregate<<<NB, 512, 0, stream>>>(h8, hscale, el, er, bucket_cursor, mid, bias, flag, out, N);
}

// Round 7
// 563.326 us; speedup vs baseline: 1.0482x; 1.0482x over previous
//
#include <hip/hip_runtime.h>
#include <hip/hip_bf16.h>
#include <stdint.h>

#define N_IN   256
#define HEADS  8
#define OUTF   32
#define HF     256   // HEADS*OUTF
#define NEG    0.2f

// ---- counting-sort CSR build params ----
#define SHIFT  8          // 256 dst nodes per coarse bucket
#define BMASK  255
#define NBMAX  512        // max coarse buckets supported (N <= 131072)
#define TILE   4096       // edges per bin_scatter block (R7: was 8192; 31.3KB LDS -> 5 blk/CU)
#define CAP    10240      // per-bucket slab capacity (avg ~8184, sigma ~90)

typedef __attribute__((ext_vector_type(8))) short  s16x8;
typedef __attribute__((ext_vector_type(4))) float  f32x4;
typedef __attribute__((ext_vector_type(4))) unsigned int u32x4;

__device__ __forceinline__ unsigned short f2b(float f) {
    unsigned int u = __float_as_uint(f);
    unsigned int r = (u + 0x7fffu + ((u >> 16) & 1u)) >> 16;
    return (unsigned short)r;
}
__device__ __forceinline__ float b2f(unsigned short u) {
    union { unsigned int i; float f; } x; x.i = ((unsigned int)u) << 16; return x.f;
}

// ---- diagnostic: fill output with sentinel ----
__global__ __launch_bounds__(256) void probe_fill(float* __restrict__ out, int n, float val)
{
    int i = blockIdx.x * blockDim.x + threadIdx.x;
    if (i < n) out[i] = val;
}

// ---- W fp32 -> bf16, once (65536 elements) ----
__global__ __launch_bounds__(256) void cvt_w(const float* __restrict__ W,
                                             unsigned short* __restrict__ Wb, int n)
{
    int i = blockIdx.x * blockDim.x + threadIdx.x;
    if (i < n) Wb[i] = f2b(W[i]);
}

// ---------------- GEMM: h = feat @ W^T, fused el/er + int8 quantization ---------
// (byte-identical to round 5 — control)
__global__ __launch_bounds__(256) void gemm_h(
    const float* __restrict__ feat,
    const unsigned short* __restrict__ Wb,
    const float* __restrict__ attn_l,
    const float* __restrict__ attn_r,
    unsigned char* __restrict__ h8,
    float* __restrict__ hscale,
    float* __restrict__ el, float* __restrict__ er,
    int* __restrict__ flag, int N)
{
    __shared__ unsigned short hs[4][16][260];   // 33.3 KB/block, per-wave slice
    int wave = (blockIdx.x * blockDim.x + threadIdx.x) >> 6;
    int lane = threadIdx.x & 63;
    int w    = (threadIdx.x >> 6) & 3;
    int m0 = wave * 16;
    if (m0 >= N) return;
    int mr = lane & 15;   // m (A) / n (B) within 16
    int kg = lane >> 4;   // k-group 0..3

    const float* ap = feat + (size_t)(m0 + mr) * N_IN + kg * 8;
    bool bad = false;
    s16x8 a[8];
#pragma unroll
    for (int kk = 0; kk < 8; kk++) {
        f32x4 lo = __builtin_nontemporal_load((const f32x4*)(ap + kk * 32));
        f32x4 hi = __builtin_nontemporal_load((const f32x4*)(ap + kk * 32 + 4));
#pragma unroll
        for (int j = 0; j < 4; j++) {
            bad |= ((__float_as_uint(lo[j]) >> 23) & 0xFF) >= 0x90;
            bad |= ((__float_as_uint(hi[j]) >> 23) & 0xFF) >= 0x90;
        }
        s16x8 r;
        r[0] = (short)f2b(lo[0]); r[1] = (short)f2b(lo[1]);
        r[2] = (short)f2b(lo[2]); r[3] = (short)f2b(lo[3]);
        r[4] = (short)f2b(hi[0]); r[5] = (short)f2b(hi[1]);
        r[6] = (short)f2b(hi[2]); r[7] = (short)f2b(hi[3]);
        a[kk] = r;
    }
    if (__ballot(bad) != 0ull && lane == 0) atomicOr(flag, 1);

    f32x4 acc[16];
#pragma unroll
    for (int nt = 0; nt < 16; nt++) {
        acc[nt] = (f32x4){0.f, 0.f, 0.f, 0.f};
        const unsigned short* bp = Wb + (size_t)(nt * 16 + mr) * N_IN + kg * 8;
#pragma unroll
        for (int kk = 0; kk < 8; kk++) {
            s16x8 b = *(const s16x8*)(bp + kk * 32);
            acc[nt] = __builtin_amdgcn_mfma_f32_16x16x32_bf16(a[kk], b, acc[nt], 0, 0, 0);
        }
    }
    // C/D layout (m89-verified): col = lane&15 (=n), row = (lane>>4)*4 + r (=m)
#pragma unroll
    for (int nt = 0; nt < 16; nt++) {
        int col = nt * 16 + mr;
#pragma unroll
        for (int r = 0; r < 4; r++) {
            int row = kg * 4 + r;
            hs[w][row][col] = f2b(acc[nt][r]);
        }
    }
    // el/er from the wave's own LDS tile (no barrier: same-wave producer).
    {
        int row = lane >> 2, hd4 = lane & 3;
#pragma unroll
        for (int p = 0; p < 2; p++) {
            int hd = hd4 + p * 4;
            const unsigned short* hp = &hs[w][row][hd * OUTF];
            const float* al = attn_l + hd * OUTF;
            const float* ar = attn_r + hd * OUTF;
            float sl = 0.f, sr = 0.f;
#pragma unroll
            for (int i = 0; i < 4; i++) {
                s16x8 hv = *(const s16x8*)(hp + i * 8);
                f32x4 al0 = *(const f32x4*)(al + i * 8);
                f32x4 al1 = *(const f32x4*)(al + i * 8 + 4);
                f32x4 ar0 = *(const f32x4*)(ar + i * 8);
                f32x4 ar1 = *(const f32x4*)(ar + i * 8 + 4);
#pragma unroll
                for (int j = 0; j < 4; j++) {
                    float v = b2f((unsigned short)hv[j]);
                    sl += v * al0[j]; sr += v * ar0[j];
                }
#pragma unroll
                for (int j = 0; j < 4; j++) {
                    float v = b2f((unsigned short)hv[4 + j]);
                    sl += v * al1[j]; sr += v * ar1[j];
                }
            }
            el[(size_t)(m0 + row) * HEADS + hd] = sl;
            er[(size_t)(m0 + row) * HEADS + hd] = sr;
        }
    }
    // int8 quantize: lane -> (row = lane>>2, quarter q4 = lane&3, 64 feats each)
    {
        int row = lane >> 2, q4 = lane & 3;
        unsigned int mxb = 0;
#pragma unroll
        for (int i = 0; i < 8; i++) {
            s16x8 hv = *(const s16x8*)(&hs[w][row][q4 * 64 + i * 8]);
#pragma unroll
            for (int j = 0; j < 8; j++) {
                unsigned int b = ((unsigned int)(unsigned short)hv[j]) & 0x7fffu;
                mxb = b > mxb ? b : mxb;
            }
        }
        mxb = max(mxb, (unsigned int)__shfl_xor((int)mxb, 1));
        mxb = max(mxb, (unsigned int)__shfl_xor((int)mxb, 2));
        float mx = b2f((unsigned short)mxb);
        float scale = mx * (1.0f / 127.0f);
        float invs  = (mx > 0.f) ? 127.0f / mx : 0.f;
        if (q4 == 0) hscale[m0 + row] = scale;
#pragma unroll
        for (int c = 0; c < 4; c++) {      // 4 chunks of 16 feats -> 16 B store
            u32x4 wout;
#pragma unroll
            for (int p = 0; p < 4; p++) {
                unsigned int wrd = 0;
#pragma unroll
                for (int k = 0; k < 4; k++) {
                    float v = b2f(hs[w][row][q4 * 64 + c * 16 + p * 4 + k]);
                    int qi = (int)rintf(v * invs) + 128;
                    qi = min(max(qi, 0), 255);
                    wrd |= ((unsigned int)qi) << (8 * k);
                }
                wout[p] = wrd;
            }
            *(u32x4*)(h8 + (size_t)(m0 + row) * HF + q4 * 64 + c * 16) = wout;
        }
    }
}

// ================ CSR build via two-level counting sort (slab mid) =================
// R7: TILE 4096 -> LDS 31.3KB -> 5 blocks/CU, 782 blocks (was 2 blocks/CU, 391).
// Pass-1 dst load is now a REGULAR load (pass 2 re-reads it from L2).
__global__ __launch_bounds__(256) void bin_scatter(
    const int* __restrict__ src, const int* __restrict__ dst,
    int* __restrict__ bucket_cursor, unsigned int* __restrict__ mid,
    int* __restrict__ flag, int E, int N, int NB)
{
    __shared__ int hist[NBMAX];    // counts, then exclusive local base
    __shared__ int cur[NBMAX];
    __shared__ int gbase[NBMAX];
    __shared__ int part[256];
    __shared__ unsigned int  sorted[TILE];
    __shared__ unsigned short sortedb[TILE];
    int t = threadIdx.x;
#pragma unroll
    for (int i = t; i < NBMAX; i += 256) hist[i] = 0;
    __syncthreads();
    int tb = blockIdx.x * TILE;
    int cnt = min(TILE, E - tb);

    // pass 1: count buckets in tile (regular load: dst is re-read in pass 2)
#pragma unroll
    for (int i = 0; i < TILE / 256; i++) {
        int e = tb + t + i * 256;
        if (e < E) {
            int d = dst[e];
            d = min(max(d, 0), N - 1);
            atomicAdd(&hist[d >> SHIFT], 1);
        }
    }
    __syncthreads();

    // reserve slab space per bucket (cursor zero-init; final value = count)
    for (int b = t; b < NB; b += 256) {
        int c = hist[b];
        int gb = c ? atomicAdd(&bucket_cursor[b], c) : 0;
        gbase[b] = gb;
        if (c && gb + c > CAP) atomicOr(flag, 1);   // slab overflow -> poison
    }

    // exclusive scan of hist (NBMAX=512 entries, 2 per thread);
    // safe: hist is overwritten only after the scan's first barrier, which all
    // threads reach only after their reserve-reads above.
    int b0 = 2 * t, b1 = 2 * t + 1;
    int c0 = hist[b0], c1 = hist[b1];
    part[t] = c0 + c1;
    __syncthreads();
    for (int off = 1; off < 256; off <<= 1) {
        int y = (t >= off) ? part[t - off] : 0;
        __syncthreads();
        part[t] += y;
        __syncthreads();
    }
    int pb = part[t] - (c0 + c1);          // exclusive over pair-groups
    hist[b0] = pb;      hist[b1] = pb + c0; // local exclusive base
    cur[b0]  = pb;      cur[b1]  = pb + c0;
    __syncthreads();

    // pass 2: place tile's edges into LDS grouped by bucket
#pragma unroll
    for (int i = 0; i < TILE / 256; i++) {
        int e = tb + t + i * 256;
        if (e < E) {
            int d = dst[e]; d = min(max(d, 0), N - 1);
            int s = src[e]; s = min(max(s, 0), N - 1);
            int b = d >> SHIFT;
            int p = atomicAdd(&cur[b], 1);
            sorted[p]  = ((unsigned int)s << SHIFT) | (unsigned int)(d & BMASK);
            sortedb[p] = (unsigned short)b;
        }
    }
    __syncthreads();

    // write out: consecutive i within a bucket -> consecutive slab addresses
    for (int i = t; i < cnt; i += 256) {
        int b = sortedb[i];
        int idx = gbase[b] + (i - hist[b]);
        if (idx < CAP) mid[(size_t)b * CAP + idx] = sorted[i];
    }
}

// Phase A2: exclusive scan of final bucket counts -> compact bases.
__global__ __launch_bounds__(512) void scan_buckets(
    const int* __restrict__ bucket_cursor, int* __restrict__ bucket_base, int NB)
{
    __shared__ int lds[512];
    int t = threadIdx.x;
    int v = (t < NB) ? bucket_cursor[t] : 0;
    lds[t] = v;
    __syncthreads();
    for (int off = 1; off < 512; off <<= 1) {
        int y = (t >= off) ? lds[t - off] : 0;
        __syncthreads();
        lds[t] += y;
        __syncthreads();
    }
    if (t < NB) bucket_base[t] = lds[t] - v;
}

// Phase C: one block per coarse bucket.
__global__ __launch_bounds__(256) void bucket_sort(
    const unsigned int* __restrict__ mid,
    const int* __restrict__ bucket_base, const int* __restrict__ bucket_cursor,
    int* __restrict__ offs, int* __restrict__ ssorted, int N, int E, int NB)
{
    __shared__ int hist[256];
    __shared__ int lds[256];
    __shared__ int cur[256];
    int b = blockIdx.x;
    int t = threadIdx.x;
    hist[t] = 0;
    __syncthreads();
    int base = bucket_base[b];
    int cnt  = min(bucket_cursor[b], CAP);
    const unsigned int* ms = mid + (size_t)b * CAP;
    for (int i = t; i < cnt; i += 256) {
        unsigned int v = ms[i];
        atomicAdd(&hist[v & BMASK], 1);
    }
    __syncthreads();
    int c = hist[t];
    lds[t] = c;
    __syncthreads();
    for (int off = 1; off < 256; off <<= 1) {
        int y = (t >= off) ? lds[t - off] : 0;
        __syncthreads();
        lds[t] += y;
        __syncthreads();
    }
    int excl = lds[t] - c;
    cur[t] = excl;
    int node = (b << SHIFT) + t;
    if (node < N) offs[node] = base + excl;
    if (b == NB - 1 && t == 0) offs[N] = E;
    __syncthreads();
    for (int i = t; i < cnt; i += 256) {
        unsigned int v = ms[i];
        int p = atomicAdd(&cur[v & BMASK], 1);
        ssorted[base + p] = (int)(v >> SHIFT);
    }
}

// ---------------- Aggregate: int8 payload, 2-deep pipeline (round-5 control) ------
// num_i = sum_j (a_j*scale_j)*u_ji - 128*sum_j(a_j*scale_j); out = num/sum(a)+bias.
// Lane layout: slot = lane>>4 (edge 0..3), g = lane&15 (16 feats = 16 B each).
__global__ __launch_bounds__(256) void aggregate(
    const unsigned char* __restrict__ h8,
    const float* __restrict__ hscale,
    const float* __restrict__ el, const float* __restrict__ er,
    const int* __restrict__ offs, const int* __restrict__ ssorted,
    const float* __restrict__ bias,
    const int* __restrict__ flag,
    float* __restrict__ out, int N, int E)
{
    int wave = blockIdx.x * 4 + (threadIdx.x >> 6);
    int lane = threadIdx.x & 63;
    if (wave >= N) return;
    int node = wave;
    int flagv = flag[0];
    int e0 = offs[node], e1 = offs[node + 1];
    e0 = min(max(e0, 0), E);
    e1 = min(max(e1, e0), E);

    int slot = lane >> 4;
    int g    = lane & 15;
    int hg   = g >> 1;

    float er_d = er[node * HEADS + hg];
    float s_acc = 0.f;     // sum a
    float sb_acc = 0.f;    // sum a*scale (for -128 bias correction)
    float acc[16];
#pragma unroll
    for (int i = 0; i < 16; i++) acc[i] = 0.f;

    if (e0 < e1) {
        int jA = e0 + slot;
        int sA = __builtin_nontemporal_load(&ssorted[jA]);
        int sB = __builtin_nontemporal_load(&ssorted[jA + 4]);
        bool vA = jA < e1;
        bool vB = (jA + 4) < e1;
        sA = min(max(sA, 0), N - 1);
        int snA = vA ? sA : 0;
        float elA = el[snA * HEADS + hg];
        float scA = hscale[snA];
        u32x4 hA = *(const u32x4*)(h8 + (size_t)snA * HF + g * 16);

        for (int j0 = e0; j0 < e1; j0 += 4) {
            int sC = __builtin_nontemporal_load(&ssorted[j0 + 8 + slot]);
            int sBc = min(max(sB, 0), N - 1);
            int snB = vB ? sBc : 0;
            float elB = el[snB * HEADS + hg];
            float scB = hscale[snB];
            u32x4 hB = *(const u32x4*)(h8 + (size_t)snB * HF + g * 16);
            __builtin_amdgcn_sched_barrier(0);   // pin load-issue before compute
            float e = elA + er_d;
            e = fmaxf(e, NEG * e);               // leaky relu, NEG in (0,1)
            float a = vA ? __expf(e) : 0.f;
            s_acc += a;
            float as2 = a * scA;
            sb_acc += as2;
#pragma unroll
            for (int p = 0; p < 4; p++) {        // decode 16 biased-uint8
                unsigned int wrd = hA[p];
                acc[p*4+0] += as2 * (float)(wrd & 0xffu);
                acc[p*4+1] += as2 * (float)((wrd >> 8) & 0xffu);
                acc[p*4+2] += as2 * (float)((wrd >> 16) & 0xffu);
                acc[p*4+3] += as2 * (float)(wrd >> 24);
            }
            vA = vB; elA = elB; scA = scB; hA = hB;
            sB = sC; vB = (j0 + 8 + slot) < e1;
        }
    }

    s_acc += __shfl_xor(s_acc, 16);
    s_acc += __shfl_xor(s_acc, 32);
    sb_acc += __shfl_xor(sb_acc, 16);
    sb_acc += __shfl_xor(sb_acc, 32);
#pragma unroll
    for (int i = 0; i < 16; i++) {
        acc[i] += __shfl_xor(acc[i], 16);
        acc[i] += __shfl_xor(acc[i], 32);
    }
    float inv = (s_acc > 0.f) ? 1.f / s_acc : 0.f;

    if (slot == 0) {
        int fo = g * 16;
        bool badv = !__builtin_isfinite(s_acc);
        float vbuf[16];
#pragma unroll
        for (int i = 0; i < 16; i++) {
            float v = (acc[i] - 128.0f * sb_acc) * inv + bias[fo + i];
            badv |= !__builtin_isfinite(v);
            vbuf[i] = v;
        }
        if (flagv) {
#pragma unroll
            for (int i = 0; i < 16; i++) vbuf[i] = 555.0f;
        } else if (badv) {
#pragma unroll
            for (int i = 0; i < 16; i++) vbuf[i] = 777.0f;
        }
#pragma unroll
        for (int q = 0; q < 4; q++) {
            f32x4 o = { vbuf[q*4+0], vbuf[q*4+1], vbuf[q*4+2], vbuf[q*4+3] };
            __builtin_nontemporal_store(o, (f32x4*)(out + (size_t)node * HF + fo + q * 4));
        }
    }
}

extern "C" void kernel_launch(void* const* d_in, const int* in_sizes, int n_in,
                              void* d_out, int out_size, void* d_ws, size_t ws_size,
                              hipStream_t stream)
{
    const float* feat   = (const float*)d_in[0];
    const int*   src    = (const int*)d_in[1];
    const int*   dst    = (const int*)d_in[2];
    const float* fc_w   = (const float*)d_in[3];
    const float* attn_l = (const float*)d_in[4];
    const float* attn_r = (const float*)d_in[5];
    const float* bias   = (const float*)d_in[6];
    float* out = (float*)d_out;

    const int N = in_sizes[0] / N_IN;
    const int E = in_sizes[1];
    const int NB = (N + 255) >> SHIFT;

    char* ws = (char*)d_ws;
    size_t off = 0;
    auto alloc = [&](size_t bytes) -> char* {
        char* p = ws + off;
        off = (off + bytes + 255) & ~(size_t)255;
        return p;
    };
    // bucket_cursor + flag contiguous -> single memset
    int* bucket_cursor = (int*)alloc((size_t)NBMAX * 4 + 256);
    int* flag          = bucket_cursor + NBMAX;
    int* bucket_base   = (int*)alloc((size_t)NBMAX * 4);
    unsigned int* mid  = (unsigned int*)alloc((size_t)NB * CAP * 4);
    int* ssorted       = (int*)alloc((size_t)(E + 64) * 4);   // +64 pad for prefetch
    int* offs          = (int*)alloc((size_t)(N + 1) * 4);
    float* el          = (float*)alloc((size_t)N * HEADS * 4);
    float* er          = (float*)alloc((size_t)N * HEADS * 4);
    unsigned char* h8  = (unsigned char*)alloc((size_t)N * HF);
    float* hscale      = (float*)alloc((size_t)N * 4);
    unsigned short* Wb = (unsigned short*)alloc((size_t)HF * N_IN * 2);

    if (off > ws_size || NB > NBMAX || N >= (1 << 24)) {
        probe_fill<<<(out_size + 255) / 256, 256, 0, stream>>>(out, out_size, 999.0f);
        return;
    }

    hipMemsetAsync(bucket_cursor, 0, (size_t)NBMAX * 4 + 256, stream);

    cvt_w<<<(HF * N_IN + 255) / 256, 256, 0, stream>>>(fc_w, Wb, HF * N_IN);
    {   // GEMM + fused el/er + int8 quantize: one wave per 16 rows
        int waves = (N + 15) / 16;
        int blocks = (waves + 3) / 4;
        gemm_h<<<blocks, 256, 0, stream>>>(feat, Wb, attn_l, attn_r, h8, hscale, el, er, flag, N);
    }
    // CSR build: slab counting sort
    int tiles = (E + TILE - 1) / TILE;
    bin_scatter<<<tiles, 256, 0, stream>>>(src, dst, bucket_cursor, mid, flag, E, N, NB);
    scan_buckets<<<1, 512, 0, stream>>>(bucket_cursor, bucket_base, NB);
    bucket_sort<<<NB, 256, 0, stream>>>(mid, bucket_base, bucket_cursor, offs, ssorted, N, E, NB);
    {   // aggregate: one wave per node, 4 waves per block
        int blocks = (N + 3) / 4;
        aggregate<<<blocks, 256, 0, stream>>>(h8, hscale, el, er, offs, ssorted, bias, flag, out, N, E);
    }
}